// Round 3
// baseline (869.002 us; speedup 1.0000x reference)
//
#include <hip/hip_runtime.h>
#include <hip/hip_bf16.h>

#define NB 262144
#define AA 10
#define DD 10
#define KK 32

// ---- bf16 helpers -----------------------------------------------------------
__device__ __forceinline__ float b2f(unsigned short h) {
    union { unsigned u; float f; } c; c.u = ((unsigned)h) << 16; return c.f;
}
__device__ __forceinline__ float bflo(unsigned w) {
    union { unsigned u; float f; } c; c.u = w << 16; return c.f;
}
__device__ __forceinline__ float bfhi(unsigned w) {
    union { unsigned u; float f; } c; c.u = w & 0xffff0000u; return c.f;
}

// Detect whether array `p` is f32 (1) or bf16 (0) by exponent-field statistics.
// bf16 data here is bounded (reps |x|<6, weights |x|<0.01) -> exponent small.
// f32 data's low-mantissa shorts have ~uniform exponent fields -> fires w.h.p.
__device__ __forceinline__ int detect_f32(const unsigned short* p, int nshorts,
                                          unsigned expthr, int lane) {
    int bad = 0;
    if (lane < nshorts) {
        unsigned short s = p[lane];
        unsigned e = (s >> 7) & 0xFFu;
        bad = (e >= expthr);
    }
    return __any(bad);
}

// One batch element per thread; per-batch state (U, V, S, aff) in VGPRs.
// Weights staged to LDS as f32 once per block (broadcast reads in the loop).
// OUTPUT IS F32 (verified round 2: bf16-packed writes half-covered the f32
// buffer -> output 1 region unwritten at exactly max|ref|).
__global__ __launch_bounds__(256, 1) void aie_kernel(
    const unsigned short* __restrict__ user_rep,   // [B,10,10]
    const unsigned short* __restrict__ item_rep,   // [B,10,10]
    const unsigned short* __restrict__ wM,         // [10,10]
    const unsigned short* __restrict__ wPu,        // [32,10]
    const unsigned short* __restrict__ wpu,        // [32]
    const unsigned short* __restrict__ wPi,        // [32,10]
    const unsigned short* __restrict__ wpi,        // [32]
    float* __restrict__ out)                       // [2*B*10] f32
{
    __shared__ float sM[100];
    __shared__ float sPu[KK * DD];
    __shared__ float sPi[KK * DD];
    __shared__ float spu[KK];
    __shared__ float spi[KK];
    __shared__ int sflags;

    const int t = threadIdx.x;

    // ---- dtype detection (wave 0 only) ----
    if (t < 64) {
        int f = 0;
        f |= detect_f32(user_rep, 64, 137, t) << 0;   // reps ~N(0,1): |x|<1024 if bf16
        f |= detect_f32(item_rep, 64, 137, t) << 1;
        f |= detect_f32(wM,  64, 125, t) << 2;        // weights ~U(-.01,.01): |x|<0.25 if bf16
        f |= detect_f32(wPu, 64, 125, t) << 3;
        f |= detect_f32(wpu, 32, 125, t) << 4;
        f |= detect_f32(wPi, 64, 125, t) << 5;
        f |= detect_f32(wpi, 32, 125, t) << 6;
        if (t == 0) sflags = f;
    }
    __syncthreads();
    const int flags = sflags;

    // ---- stage weights to LDS as f32 ----
    {
        const float* fM  = (const float*)wM;
        const float* fPu = (const float*)wPu;
        const float* fPi = (const float*)wPi;
        const float* fpu = (const float*)wpu;
        const float* fpi = (const float*)wpi;
        for (int i = t; i < 100; i += 256)
            sM[i] = (flags & 4) ? fM[i] : b2f(wM[i]);
        for (int i = t; i < KK * DD; i += 256) {
            sPu[i] = (flags & 8)  ? fPu[i] : b2f(wPu[i]);
            sPi[i] = (flags & 32) ? fPi[i] : b2f(wPi[i]);
        }
        if (t < KK) {
            spu[t] = (flags & 16) ? fpu[t] : b2f(wpu[t]);
            spi[t] = (flags & 64) ? fpi[t] : b2f(wpi[t]);
        }
    }
    __syncthreads();

    const int b = blockIdx.x * 256 + t;

    // ---- load V (item_rep) ----
    float V[AA][DD];
    if (flags & 2) {
        const float4* p = reinterpret_cast<const float4*>(
            (const float*)item_rep + (size_t)b * 100);
        #pragma unroll
        for (int j = 0; j < 25; j++) {
            float4 w = p[j];
            int f = 4 * j;
            V[f / 10][f % 10]             = w.x;
            V[(f + 1) / 10][(f + 1) % 10] = w.y;
            V[(f + 2) / 10][(f + 2) % 10] = w.z;
            V[(f + 3) / 10][(f + 3) % 10] = w.w;
        }
    } else {
        const uint2* p = reinterpret_cast<const uint2*>(item_rep + (size_t)b * 100);
        #pragma unroll
        for (int j = 0; j < 25; j++) {
            uint2 w = p[j];
            int f = 4 * j;
            V[f / 10][f % 10]             = bflo(w.x);
            V[(f + 1) / 10][(f + 1) % 10] = bfhi(w.x);
            V[(f + 2) / 10][(f + 2) % 10] = bflo(w.y);
            V[(f + 3) / 10][(f + 3) % 10] = bfhi(w.y);
        }
    }

    // ---- S[d][v] = sum_e M[d][e] * V[v][e] ----
    float S[DD][AA];
    #pragma unroll
    for (int d = 0; d < DD; d++) {
        float m[DD];
        #pragma unroll
        for (int e = 0; e < DD; e++) m[e] = sM[d * 10 + e];
        #pragma unroll
        for (int v = 0; v < AA; v++) {
            float acc = 0.f;
            #pragma unroll
            for (int e = 0; e < DD; e++) acc += m[e] * V[v][e];
            S[d][v] = acc;
        }
    }

    // ---- load U (user_rep) ----
    float U[AA][DD];
    if (flags & 1) {
        const float4* p = reinterpret_cast<const float4*>(
            (const float*)user_rep + (size_t)b * 100);
        #pragma unroll
        for (int j = 0; j < 25; j++) {
            float4 w = p[j];
            int f = 4 * j;
            U[f / 10][f % 10]             = w.x;
            U[(f + 1) / 10][(f + 1) % 10] = w.y;
            U[(f + 2) / 10][(f + 2) % 10] = w.z;
            U[(f + 3) / 10][(f + 3) % 10] = w.w;
        }
    } else {
        const uint2* p = reinterpret_cast<const uint2*>(user_rep + (size_t)b * 100);
        #pragma unroll
        for (int j = 0; j < 25; j++) {
            uint2 w = p[j];
            int f = 4 * j;
            U[f / 10][f % 10]             = bflo(w.x);
            U[(f + 1) / 10][(f + 1) % 10] = bfhi(w.x);
            U[(f + 2) / 10][(f + 2) % 10] = bflo(w.y);
            U[(f + 3) / 10][(f + 3) % 10] = bfhi(w.y);
        }
    }

    // ---- aff[u][v] = relu(sum_d U[u][d] * S[d][v]) ----
    float aff[AA][AA];
    #pragma unroll
    for (int u = 0; u < AA; u++) {
        #pragma unroll
        for (int v = 0; v < AA; v++) {
            float acc = 0.f;
            #pragma unroll
            for (int d = 0; d < DD; d++) acc += U[u][d] * S[d][v];
            aff[u][v] = fmaxf(acc, 0.f);
        }
    }

    // ---- k loop: accumulate scores ----
    float us[AA], isc[AA];
    #pragma unroll
    for (int u = 0; u < AA; u++) { us[u] = 0.f; isc[u] = 0.f; }

    #pragma unroll 2
    for (int k = 0; k < KK; k++) {
        float pu[DD], pi[DD];
        #pragma unroll
        for (int d = 0; d < DD; d++) { pu[d] = sPu[k * 10 + d]; pi[d] = sPi[k * 10 + d]; }

        float hu[AA], hi[AA];
        #pragma unroll
        for (int u = 0; u < AA; u++) {
            float acc = 0.f;
            #pragma unroll
            for (int d = 0; d < DD; d++) acc += pu[d] * U[u][d];
            hu[u] = acc;
        }
        #pragma unroll
        for (int v = 0; v < AA; v++) {
            float acc = 0.f;
            #pragma unroll
            for (int d = 0; d < DD; d++) acc += pi[d] * V[v][d];
            hi[v] = acc;
        }

        const float wu = spu[k], wi = spi[k];
        #pragma unroll
        for (int u = 0; u < AA; u++) {
            float acc = hu[u];
            #pragma unroll
            for (int v = 0; v < AA; v++) acc += hi[v] * aff[u][v];
            us[u] += wu * fmaxf(acc, 0.f);
        }
        #pragma unroll
        for (int v = 0; v < AA; v++) {
            float acc = hi[v];
            #pragma unroll
            for (int u = 0; u < AA; u++) acc += hu[u] * aff[u][v];
            isc[v] += wi * fmaxf(acc, 0.f);
        }
    }

    // ---- softmax over 10 aspects, store as F32 (5 x float2 per output) ----
    {
        float mx = us[0];
        #pragma unroll
        for (int u = 1; u < AA; u++) mx = fmaxf(mx, us[u]);
        float s = 0.f;
        #pragma unroll
        for (int u = 0; u < AA; u++) { us[u] = __expf(us[u] - mx); s += us[u]; }
        float inv = 1.f / s;
        float2* dst = reinterpret_cast<float2*>(out + (size_t)b * 10);
        #pragma unroll
        for (int j = 0; j < 5; j++)
            dst[j] = make_float2(us[2 * j] * inv, us[2 * j + 1] * inv);
    }
    {
        float mx = isc[0];
        #pragma unroll
        for (int v = 1; v < AA; v++) mx = fmaxf(mx, isc[v]);
        float s = 0.f;
        #pragma unroll
        for (int v = 0; v < AA; v++) { isc[v] = __expf(isc[v] - mx); s += isc[v]; }
        float inv = 1.f / s;
        float2* dst = reinterpret_cast<float2*>(out + (size_t)(NB + b) * 10);
        #pragma unroll
        for (int j = 0; j < 5; j++)
            dst[j] = make_float2(isc[2 * j] * inv, isc[2 * j + 1] * inv);
    }
}

extern "C" void kernel_launch(void* const* d_in, const int* in_sizes, int n_in,
                              void* d_out, int out_size, void* d_ws, size_t ws_size,
                              hipStream_t stream) {
    const unsigned short* user_rep = (const unsigned short*)d_in[0];
    const unsigned short* item_rep = (const unsigned short*)d_in[1];
    const unsigned short* wM       = (const unsigned short*)d_in[2];
    const unsigned short* wPu      = (const unsigned short*)d_in[3];
    const unsigned short* wpu      = (const unsigned short*)d_in[4];
    const unsigned short* wPi      = (const unsigned short*)d_in[5];
    const unsigned short* wpi      = (const unsigned short*)d_in[6];
    float* out                     = (float*)d_out;

    dim3 block(256);
    dim3 grid(NB / 256);
    hipLaunchKernelGGL(aie_kernel, grid, block, 0, stream,
                       user_rep, item_rep, wM, wPu, wpu, wPi, wpi, out);
}

// Round 4
// 397.417 us; speedup vs baseline: 2.1866x; 2.1866x over previous
//
#include <hip/hip_runtime.h>
#include <hip/hip_bf16.h>

#define NB 262144
#define AA 10
#define DD 10
#define KK 32

// ---- bf16 helpers -----------------------------------------------------------
static __device__ __forceinline__ float b2f(unsigned short h) {
    union { unsigned u; float f; } c; c.u = ((unsigned)h) << 16; return c.f;
}
static __device__ __forceinline__ float bflo(unsigned w) {
    union { unsigned u; float f; } c; c.u = w << 16; return c.f;
}
static __device__ __forceinline__ float bfhi(unsigned w) {
    union { unsigned u; float f; } c; c.u = w & 0xffff0000u; return c.f;
}

// f32-vs-bf16 detection by exponent-field statistics (verified rounds 2-3).
__device__ __forceinline__ int detect_f32(const unsigned short* p, int nshorts,
                                          unsigned expthr, int lane) {
    int bad = 0;
    if (lane < nshorts) {
        unsigned e = (p[lane] >> 7) & 0xFFu;
        bad = (e >= expthr);
    }
    return __any(bad);
}

// One wave per block; one batch per thread.
// Register-lean dataflow:
//   W[u][d] = sum_v relu(aff[u][v]) * V[v][d]   (aff row-at-a-time, never stored)
//   us[u]  += pu_k * relu(Pu[k]·U[u] + Pi[k]·W[u])
//   X[v][d] = sum_u relu(aff[u][v]) * U[u][d]   (aff recomputed, reversed order)
//   isc[v] += pi_k * relu(Pi[k]·V[v] + Pu[k]·X[v])
// Peak co-live register arrays: {U,V,W} or {U,V,X} ~= 310 f32 (vs 430 before).
// All global I/O staged through LDS for coalescing.
__global__ __launch_bounds__(64, 1) void aie_kernel(
    const unsigned short* __restrict__ user_rep,   // [B,10,10]
    const unsigned short* __restrict__ item_rep,   // [B,10,10]
    const unsigned short* __restrict__ wM,         // [10,10]
    const unsigned short* __restrict__ wPu,        // [32,10]
    const unsigned short* __restrict__ wpu,        // [32]
    const unsigned short* __restrict__ wPi,        // [32,10]
    const unsigned short* __restrict__ wpi,        // [32]
    float* __restrict__ out)                       // [2*B*10] f32
{
    __shared__ float sM[100];
    __shared__ float sPu[KK * DD], sPi[KK * DD], spu[KK], spi[KK];
    __shared__ float buf[6400];   // 25.6 KB: input staging, then output staging

    const int t = threadIdx.x;

    // ---- dtype detection (single wave -> result is wave-uniform) ----
    int f = 0;
    f |= detect_f32(user_rep, 64, 137, t) << 0;
    f |= detect_f32(item_rep, 64, 137, t) << 1;
    f |= detect_f32(wM,  64, 125, t) << 2;
    f |= detect_f32(wPu, 64, 125, t) << 3;
    f |= detect_f32(wpu, 32, 125, t) << 4;
    f |= detect_f32(wPi, 64, 125, t) << 5;
    f |= detect_f32(wpi, 32, 125, t) << 6;

    // ---- stage weights to LDS as f32 ----
    {
        const float* fM  = (const float*)wM;
        const float* fPu = (const float*)wPu;
        const float* fPi = (const float*)wPi;
        const float* fpu = (const float*)wpu;
        const float* fpi = (const float*)wpi;
        for (int i = t; i < 100; i += 64) sM[i] = (f & 4) ? fM[i] : b2f(wM[i]);
        for (int i = t; i < KK * DD; i += 64) {
            sPu[i] = (f & 8)  ? fPu[i] : b2f(wPu[i]);
            sPi[i] = (f & 32) ? fPi[i] : b2f(wPi[i]);
        }
        if (t < KK) {
            spu[t] = (f & 16) ? fpu[t] : b2f(wpu[t]);
            spi[t] = (f & 64) ? fpi[t] : b2f(wpi[t]);
        }
    }
    __syncthreads();

    const int blk = blockIdx.x;
    float U[AA][DD], V[AA][DD];

    // ---- stage & unpack item_rep -> V (coalesced float4 stream -> LDS) ----
    if (f & 2) {
        const float4* g = (const float4*)((const float*)item_rep + (size_t)blk * 6400);
        #pragma unroll
        for (int j = 0; j < 25; j++) ((float4*)buf)[t + 64 * j] = g[t + 64 * j];
    } else {
        const uint2* g = (const uint2*)(item_rep + (size_t)blk * 6400);
        #pragma unroll
        for (int j = 0; j < 25; j++) {
            uint2 w = g[t + 64 * j];
            ((float4*)buf)[t + 64 * j] =
                make_float4(bflo(w.x), bfhi(w.x), bflo(w.y), bfhi(w.y));
        }
    }
    __syncthreads();
    {
        const float4* mine = (const float4*)(buf + 100 * t);
        #pragma unroll
        for (int j = 0; j < 25; j++) {
            float4 w = mine[j]; int e = 4 * j;
            V[e / 10][e % 10]             = w.x;
            V[(e + 1) / 10][(e + 1) % 10] = w.y;
            V[(e + 2) / 10][(e + 2) % 10] = w.z;
            V[(e + 3) / 10][(e + 3) % 10] = w.w;
        }
    }
    __syncthreads();

    // ---- stage & unpack user_rep -> U ----
    if (f & 1) {
        const float4* g = (const float4*)((const float*)user_rep + (size_t)blk * 6400);
        #pragma unroll
        for (int j = 0; j < 25; j++) ((float4*)buf)[t + 64 * j] = g[t + 64 * j];
    } else {
        const uint2* g = (const uint2*)(user_rep + (size_t)blk * 6400);
        #pragma unroll
        for (int j = 0; j < 25; j++) {
            uint2 w = g[t + 64 * j];
            ((float4*)buf)[t + 64 * j] =
                make_float4(bflo(w.x), bfhi(w.x), bflo(w.y), bfhi(w.y));
        }
    }
    __syncthreads();
    {
        const float4* mine = (const float4*)(buf + 100 * t);
        #pragma unroll
        for (int j = 0; j < 25; j++) {
            float4 w = mine[j]; int e = 4 * j;
            U[e / 10][e % 10]             = w.x;
            U[(e + 1) / 10][(e + 1) % 10] = w.y;
            U[(e + 2) / 10][(e + 2) % 10] = w.z;
            U[(e + 3) / 10][(e + 3) % 10] = w.w;
        }
    }
    __syncthreads();

    // ---- phase 2: W[u][d] = sum_v relu(aff[u][v]) V[v][d], aff row-wise ----
    float W[AA][DD];
    #pragma unroll
    for (int u = 0; u < AA; u++) {
        float um[DD];
        #pragma unroll
        for (int e = 0; e < DD; e++) {
            float a = U[u][0] * sM[e];
            #pragma unroll
            for (int d = 1; d < DD; d++) a += U[u][d] * sM[d * 10 + e];
            um[e] = a;
        }
        float wrow[DD];
        #pragma unroll
        for (int d = 0; d < DD; d++) wrow[d] = 0.f;
        #pragma unroll
        for (int v = 0; v < AA; v++) {
            float r = um[0] * V[v][0];
            #pragma unroll
            for (int e = 1; e < DD; e++) r += um[e] * V[v][e];
            r = fmaxf(r, 0.f);
            #pragma unroll
            for (int d = 0; d < DD; d++) wrow[d] += r * V[v][d];
        }
        #pragma unroll
        for (int d = 0; d < DD; d++) W[u][d] = wrow[d];
    }

    // ---- phase 3: k-loop A (user branch) ----
    float us[AA];
    #pragma unroll
    for (int u = 0; u < AA; u++) us[u] = 0.f;
    #pragma unroll 2
    for (int k = 0; k < KK; k++) {
        float pu[DD], pi[DD];
        #pragma unroll
        for (int d = 0; d < DD; d++) { pu[d] = sPu[k * 10 + d]; pi[d] = sPi[k * 10 + d]; }
        const float wk = spu[k];
        #pragma unroll
        for (int u = 0; u < AA; u++) {
            float a = pu[0] * U[u][0], b = pi[0] * W[u][0];
            #pragma unroll
            for (int d = 1; d < DD; d++) { a += pu[d] * U[u][d]; b += pi[d] * W[u][d]; }
            us[u] += wk * fmaxf(a + b, 0.f);
        }
    }

    // ---- softmax(us) -> buf[11t+u] ----
    {
        float mx = us[0];
        #pragma unroll
        for (int u = 1; u < AA; u++) mx = fmaxf(mx, us[u]);
        float s = 0.f;
        #pragma unroll
        for (int u = 0; u < AA; u++) { us[u] = __expf(us[u] - mx); s += us[u]; }
        float inv = 1.f / s;
        #pragma unroll
        for (int u = 0; u < AA; u++) buf[11 * t + u] = us[u] * inv;
    }

    // ---- phase 5: X[v][d] = sum_u relu(aff[u][v]) U[u][d] ----
    // um recomputed in REVERSED summation order: different FP expression tree
    // prevents CSE keeping phase-2 values alive (register pressure control).
    float X[AA][DD];
    #pragma unroll
    for (int u = 0; u < AA; u++) {
        float um[DD];
        #pragma unroll
        for (int e = 0; e < DD; e++) {
            float a = U[u][DD - 1] * sM[(DD - 1) * 10 + e];
            #pragma unroll
            for (int d = DD - 2; d >= 0; d--) a += U[u][d] * sM[d * 10 + e];
            um[e] = a;
        }
        #pragma unroll
        for (int v = 0; v < AA; v++) {
            float r = um[DD - 1] * V[v][DD - 1];
            #pragma unroll
            for (int e = DD - 2; e >= 0; e--) r += um[e] * V[v][e];
            r = fmaxf(r, 0.f);
            #pragma unroll
            for (int d = 0; d < DD; d++) {
                if (u == 0) X[v][d] = r * U[u][d];
                else        X[v][d] += r * U[u][d];
            }
        }
    }

    // ---- phase 6: k-loop B (item branch) ----
    float isc[AA];
    #pragma unroll
    for (int v = 0; v < AA; v++) isc[v] = 0.f;
    #pragma unroll 2
    for (int k = 0; k < KK; k++) {
        float pu[DD], pi[DD];
        #pragma unroll
        for (int d = 0; d < DD; d++) { pu[d] = sPu[k * 10 + d]; pi[d] = sPi[k * 10 + d]; }
        const float wk = spi[k];
        #pragma unroll
        for (int v = 0; v < AA; v++) {
            float a = pi[0] * V[v][0], b = pu[0] * X[v][0];
            #pragma unroll
            for (int d = 1; d < DD; d++) { a += pi[d] * V[v][d]; b += pu[d] * X[v][d]; }
            isc[v] += wk * fmaxf(a + b, 0.f);
        }
    }

    // ---- softmax(isc) -> buf[704 + 11t+u] ----
    {
        float mx = isc[0];
        #pragma unroll
        for (int v = 1; v < AA; v++) mx = fmaxf(mx, isc[v]);
        float s = 0.f;
        #pragma unroll
        for (int v = 0; v < AA; v++) { isc[v] = __expf(isc[v] - mx); s += isc[v]; }
        float inv = 1.f / s;
        #pragma unroll
        for (int v = 0; v < AA; v++) buf[704 + 11 * t + v] = isc[v] * inv;
    }
    __syncthreads();

    // ---- coalesced output stores (float2 streams) ----
    {
        float2* o0 = (float2*)(out + (size_t)blk * 640);
        float2* o1 = (float2*)(out + (size_t)NB * 10 + (size_t)blk * 640);
        #pragma unroll
        for (int j = 0; j < 5; j++) {
            int m = t + 64 * j;
            int i = m / 5;
            int u = 2 * (m - 5 * i);
            o0[m] = make_float2(buf[11 * i + u],       buf[11 * i + u + 1]);
            o1[m] = make_float2(buf[704 + 11 * i + u], buf[704 + 11 * i + u + 1]);
        }
    }
}

extern "C" void kernel_launch(void* const* d_in, const int* in_sizes, int n_in,
                              void* d_out, int out_size, void* d_ws, size_t ws_size,
                              hipStream_t stream) {
    const unsigned short* user_rep = (const unsigned short*)d_in[0];
    const unsigned short* item_rep = (const unsigned short*)d_in[1];
    const unsigned short* wM       = (const unsigned short*)d_in[2];
    const unsigned short* wPu      = (const unsigned short*)d_in[3];
    const unsigned short* wpu      = (const unsigned short*)d_in[4];
    const unsigned short* wPi      = (const unsigned short*)d_in[5];
    const unsigned short* wpi      = (const unsigned short*)d_in[6];
    float* out                     = (float*)d_out;

    dim3 block(64);
    dim3 grid(NB / 64);   // 4096 blocks
    hipLaunchKernelGGL(aie_kernel, grid, block, 0, stream,
                       user_rep, item_rep, wM, wPu, wpu, wPi, wpi, out);
}